// Round 7
// baseline (1739.187 us; speedup 1.0000x reference)
//
#include <hip/hip_runtime.h>
#include <hip/hip_cooperative_groups.h>

namespace cg = cooperative_groups;

#define B_    4
#define S_    512
#define D_    64
#define DFF_  256
#define N_    2048          // B_*S_
#define GWG   256           // 1 block per CU (cooperative-safe)
#define TPB   1024          // 16 waves/block = 4 waves/SIMD
#define RPW   8             // rows per workgroup
#define NSTEPS 4
#define DTs   0.25f

__constant__ float A_tab[6][5] = {
    {0.f, 0.f, 0.f, 0.f, 0.f},
    {0.25f, 0.f, 0.f, 0.f, 0.f},
    {3.0f/32.0f, 9.0f/32.0f, 0.f, 0.f, 0.f},
    {1932.0f/2197.0f, -7200.0f/2197.0f, 7296.0f/2197.0f, 0.f, 0.f},
    {439.0f/216.0f, -8.0f, 3680.0f/513.0f, -845.0f/4104.0f, 0.f},
    {-8.0f/27.0f, 2.0f, -3544.0f/2565.0f, 1859.0f/4104.0f, -11.0f/40.0f}};
__constant__ float B_tab[6] = {16.0f/135.0f, 0.0f, 6656.0f/12825.0f,
                               28561.0f/56430.0f, -9.0f/50.0f, 2.0f/55.0f};

__global__ __launch_bounds__(TPB, 4) void ode_enc_kernel(
    const float* __restrict__ x,
    const float* __restrict__ Wq, const float* __restrict__ bq,
    const float* __restrict__ Wk, const float* __restrict__ bk,
    const float* __restrict__ Wv, const float* __restrict__ bv,
    const float* __restrict__ Wo, const float* __restrict__ bo,
    const float* __restrict__ W1, const float* __restrict__ b1,
    const float* __restrict__ W2, const float* __restrict__ b2,
    float* __restrict__ out,
    float* __restrict__ g_k,    // [2][N_*D_] ping-pong K
    float* __restrict__ g_v)    // [2][N_*D_] ping-pong V
{
    cg::grid_group grid = cg::this_grid();
    const int wg   = blockIdx.x;
    const int tid  = threadIdx.x;
    const int lane = tid & 63;
    const int wv   = tid >> 6;            // wave id 0..15
    // XCD-aware swizzle: each XCD's 32 blocks serve one contiguous sid chunk
    const int sid  = (wg & 7) * 32 + (wg >> 3);
    const int row0  = sid * RPW;
    const int krow0 = (sid >> 6) * S_;    // batch base (64 sids per batch)

    const int r_own = wv & 7;             // for tid<512: owned (row, col)
    const int c_own = lane;

    __shared__ float sy[RPW][D_];         // stage input
    __shared__ float sqs[RPW][D_];        // Q projection (pre-scaled)
    __shared__ float satt[RPW][D_];       // attention output
    __shared__ float sh[RPW][D_];         // FFN input
    __shared__ float st[RPW][DFF_];       // relu(h@W1+b1)
    __shared__ float U[10240];            // partials union (40 KB)

    // per-thread state (tid<512 only): y and RK slopes in REGISTERS
    float ys_reg = 0.f;
    if (tid < 512) ys_reg = x[(row0 + r_own) * D_ + c_own];
    float k1r = 0.f, k2r = 0.f, k3r = 0.f, k4r = 0.f, k5r = 0.f;
    const float bq_r = bq[c_own], bk_r = bk[c_own], bv_r = bv[c_own];
    const float bo_r = bo[c_own], b2_r = b2[c_own];
    const float b1_r = b1[tid & 255];
    const float SC = 0.51006702f;         // log2(e)/sqrt(8)

    for (int step = 0; step < NSTEPS; ++step) {
        for (int stage = 0; stage < 6; ++stage) {
            const int buf = (step * 6 + stage) & 1;

            // ---------- P1: RK stage input (branchless tableau) ----------
            float stin = 0.f;
            if (tid < 512) {
                stin = ys_reg;
                stin = fmaf(DTs * A_tab[stage][0], k1r, stin);
                stin = fmaf(DTs * A_tab[stage][1], k2r, stin);
                stin = fmaf(DTs * A_tab[stage][2], k3r, stin);
                stin = fmaf(DTs * A_tab[stage][3], k4r, stin);
                stin = fmaf(DTs * A_tab[stage][4], k5r, stin);
                sy[r_own][c_own] = stin;
            }
            __syncthreads();   // SYNC_A (also orders U reuse)

            // ---------- QKV compute: waves 0..11 = (mat, d-quarter) ----------
            if (wv < 12) {
                const int mat = wv >> 2, p = wv & 3;
                const float* Wm = (mat == 0) ? Wq : (mat == 1) ? Wk : Wv;
                float acc[8];
                #pragma unroll
                for (int r = 0; r < 8; ++r) acc[r] = 0.f;
                #pragma unroll
                for (int i4 = 0; i4 < 4; ++i4) {
                    const int dd0 = p * 16 + i4 * 4;
                    const float w0 = Wm[(dd0 + 0) * D_ + lane];
                    const float w1 = Wm[(dd0 + 1) * D_ + lane];
                    const float w2 = Wm[(dd0 + 2) * D_ + lane];
                    const float w3 = Wm[(dd0 + 3) * D_ + lane];
                    #pragma unroll
                    for (int r = 0; r < 8; ++r) {
                        const float4 s4 = *(const float4*)&sy[r][dd0];
                        acc[r] = fmaf(s4.x, w0, fmaf(s4.y, w1, fmaf(s4.z, w2, fmaf(s4.w, w3, acc[r]))));
                    }
                }
                #pragma unroll
                for (int r = 0; r < 8; ++r) U[(wv * 8 + r) * 64 + lane] = acc[r];
            }
            __syncthreads();   // SYNC_B

            // ---------- QKV combine (tid<512) ----------
            if (tid < 512) {
                float qa = bq_r, ka = bk_r, va = bv_r;
                #pragma unroll
                for (int p = 0; p < 4; ++p) {
                    qa += U[((0 + p) * 8 + r_own) * 64 + c_own];
                    ka += U[((4 + p) * 8 + r_own) * 64 + c_own];
                    va += U[((8 + p) * 8 + r_own) * 64 + c_own];
                }
                sqs[r_own][c_own] = qa * SC;   // pre-scaled Q
                const size_t kidx = ((size_t)buf * N_ + row0 + r_own) * D_ + c_own;
                g_k[kidx] = ka;
                g_v[kidx] = va;
            }
            grid.sync();       // K/V of the whole batch visible

            // ---------- attention: wave = 32-key slice, lane = (head, row) ----------
            // 8 lanes sharing a head read identical addresses (broadcast);
            // K+V read exactly once per block per stage.
            {
                const int h = lane & 7;        // head
                const int r = lane >> 3;       // q-row
                float qv[8];
                {
                    const float4 qa = *(const float4*)&sqs[r][h * 8];
                    const float4 qb = *(const float4*)&sqs[r][h * 8 + 4];
                    qv[0] = qa.x; qv[1] = qa.y; qv[2] = qa.z; qv[3] = qa.w;
                    qv[4] = qb.x; qv[5] = qb.y; qv[6] = qb.z; qv[7] = qb.w;
                }
                const float* kb = g_k + ((size_t)buf * N_ + krow0 + wv * 32) * D_ + h * 8;
                const float* vb = g_v + ((size_t)buf * N_ + krow0 + wv * 32) * D_ + h * 8;

                float m = -1e30f, l = 0.f;
                float acc8[8];
                #pragma unroll
                for (int d = 0; d < 8; ++d) acc8[d] = 0.f;

                for (int j0 = 0; j0 < 32; j0 += 4) {
                    float4 kA[4], kB[4], vA[4], vB[4];
                    #pragma unroll
                    for (int u = 0; u < 4; ++u) {
                        const float* kr = kb + (size_t)(j0 + u) * D_;
                        kA[u] = *(const float4*)kr;
                        kB[u] = *(const float4*)(kr + 4);
                    }
                    #pragma unroll
                    for (int u = 0; u < 4; ++u) {
                        const float* vr = vb + (size_t)(j0 + u) * D_;
                        vA[u] = *(const float4*)vr;
                        vB[u] = *(const float4*)(vr + 4);
                    }
                    float s0, s1, s2, s3;
                    s0 = fmaf(qv[0],kA[0].x,fmaf(qv[1],kA[0].y,fmaf(qv[2],kA[0].z,fmaf(qv[3],kA[0].w,
                         fmaf(qv[4],kB[0].x,fmaf(qv[5],kB[0].y,fmaf(qv[6],kB[0].z,qv[7]*kB[0].w)))))));
                    s1 = fmaf(qv[0],kA[1].x,fmaf(qv[1],kA[1].y,fmaf(qv[2],kA[1].z,fmaf(qv[3],kA[1].w,
                         fmaf(qv[4],kB[1].x,fmaf(qv[5],kB[1].y,fmaf(qv[6],kB[1].z,qv[7]*kB[1].w)))))));
                    s2 = fmaf(qv[0],kA[2].x,fmaf(qv[1],kA[2].y,fmaf(qv[2],kA[2].z,fmaf(qv[3],kA[2].w,
                         fmaf(qv[4],kB[2].x,fmaf(qv[5],kB[2].y,fmaf(qv[6],kB[2].z,qv[7]*kB[2].w)))))));
                    s3 = fmaf(qv[0],kA[3].x,fmaf(qv[1],kA[3].y,fmaf(qv[2],kA[3].z,fmaf(qv[3],kA[3].w,
                         fmaf(qv[4],kB[3].x,fmaf(qv[5],kB[3].y,fmaf(qv[6],kB[3].z,qv[7]*kB[3].w)))))));

                    const float bm = fmaxf(fmaxf(s0, s1), fmaxf(s2, s3));
                    if (bm > m + 8.f) {        // deferred-rescale (T13)
                        const float al = exp2f(m - bm);
                        m = bm; l *= al;
                        #pragma unroll
                        for (int d = 0; d < 8; ++d) acc8[d] *= al;
                    }
                    const float p0 = exp2f(s0 - m);
                    const float p1 = exp2f(s1 - m);
                    const float p2 = exp2f(s2 - m);
                    const float p3 = exp2f(s3 - m);
                    l += (p0 + p1) + (p2 + p3);
                    acc8[0] = fmaf(p0,vA[0].x,fmaf(p1,vA[1].x,fmaf(p2,vA[2].x,fmaf(p3,vA[3].x,acc8[0]))));
                    acc8[1] = fmaf(p0,vA[0].y,fmaf(p1,vA[1].y,fmaf(p2,vA[2].y,fmaf(p3,vA[3].y,acc8[1]))));
                    acc8[2] = fmaf(p0,vA[0].z,fmaf(p1,vA[1].z,fmaf(p2,vA[2].z,fmaf(p3,vA[3].z,acc8[2]))));
                    acc8[3] = fmaf(p0,vA[0].w,fmaf(p1,vA[1].w,fmaf(p2,vA[2].w,fmaf(p3,vA[3].w,acc8[3]))));
                    acc8[4] = fmaf(p0,vB[0].x,fmaf(p1,vB[1].x,fmaf(p2,vB[2].x,fmaf(p3,vB[3].x,acc8[4]))));
                    acc8[5] = fmaf(p0,vB[0].y,fmaf(p1,vB[1].y,fmaf(p2,vB[2].y,fmaf(p3,vB[3].y,acc8[5]))));
                    acc8[6] = fmaf(p0,vB[0].z,fmaf(p1,vB[1].z,fmaf(p2,vB[2].z,fmaf(p3,vB[3].z,acc8[6]))));
                    acc8[7] = fmaf(p0,vB[0].w,fmaf(p1,vB[1].w,fmaf(p2,vB[2].w,fmaf(p3,vB[3].w,acc8[7]))));
                }
                // write partial (acc8, m, l) for (key-slice wv, row r, head h)
                const int pb = ((wv * 8 + r) * 8 + h) * 10;
                #pragma unroll
                for (int d = 0; d < 8; ++d) U[pb + d] = acc8[d];
                U[pb + 8] = m;
                U[pb + 9] = l;
            }
            __syncthreads();   // SYNC_C1

            // ---------- merge the 16 key-slice partials (tid<512) ----------
            if (tid < 512) {
                const int h = c_own >> 3, d = c_own & 7;
                float M = -1e30f;
                float mw[16];
                #pragma unroll
                for (int w = 0; w < 16; ++w) {
                    mw[w] = U[((w * 8 + r_own) * 8 + h) * 10 + 8];
                    M = fmaxf(M, mw[w]);
                }
                float L = 0.f, A = 0.f;
                #pragma unroll
                for (int w = 0; w < 16; ++w) {
                    const int pb = ((w * 8 + r_own) * 8 + h) * 10;
                    const float wt = exp2f(mw[w] - M);
                    L = fmaf(U[pb + 9], wt, L);
                    A = fmaf(U[pb + d], wt, A);
                }
                satt[r_own][c_own] = A * __builtin_amdgcn_rcpf(L);
            }
            __syncthreads();   // SYNC_C2

            // ---------- Wo compute: wave wv = 4-row d-slice ----------
            {
                const int dd0 = wv * 4;
                const float w0 = Wo[(dd0 + 0) * D_ + lane];
                const float w1 = Wo[(dd0 + 1) * D_ + lane];
                const float w2 = Wo[(dd0 + 2) * D_ + lane];
                const float w3 = Wo[(dd0 + 3) * D_ + lane];
                float acc[8];
                #pragma unroll
                for (int r = 0; r < 8; ++r) {
                    const float4 s4 = *(const float4*)&satt[r][dd0];
                    acc[r] = fmaf(s4.x, w0, fmaf(s4.y, w1, fmaf(s4.z, w2, s4.w * w3)));
                }
                #pragma unroll
                for (int r = 0; r < 8; ++r) U[(wv * 8 + r) * 64 + lane] = acc[r];
            }
            __syncthreads();   // SYNC_D

            // ---------- Wo combine (tid<512) ----------
            float so_reg = 0.f;
            if (tid < 512) {
                float a = bo_r;
                #pragma unroll
                for (int w = 0; w < 16; ++w) a += U[(w * 8 + r_own) * 64 + c_own];
                so_reg = a;
                sh[r_own][c_own] = stin + a;
            }
            __syncthreads();   // SYNC_E

            // ---------- FFN1 compute: thread = (c2, d-quarter) ----------
            {
                const int c2 = tid & 255, p = tid >> 8;
                float acc[8];
                #pragma unroll
                for (int r = 0; r < 8; ++r) acc[r] = 0.f;
                #pragma unroll
                for (int i4 = 0; i4 < 4; ++i4) {
                    const int dd0 = p * 16 + i4 * 4;
                    const float w0 = W1[(dd0 + 0) * DFF_ + c2];
                    const float w1 = W1[(dd0 + 1) * DFF_ + c2];
                    const float w2 = W1[(dd0 + 2) * DFF_ + c2];
                    const float w3 = W1[(dd0 + 3) * DFF_ + c2];
                    #pragma unroll
                    for (int r = 0; r < 8; ++r) {
                        const float4 s4 = *(const float4*)&sh[r][dd0];
                        acc[r] = fmaf(s4.x, w0, fmaf(s4.y, w1, fmaf(s4.z, w2, fmaf(s4.w, w3, acc[r]))));
                    }
                }
                #pragma unroll
                for (int r = 0; r < 8; ++r) U[(p * 8 + r) * 256 + c2] = acc[r];
            }
            __syncthreads();   // SYNC_F

            // ---------- FFN1 combine: thread = (c2, row-pair) ----------
            {
                const int c2 = tid & 255, rb = (tid >> 8) * 2;
                #pragma unroll
                for (int i = 0; i < 2; ++i) {
                    const int r = rb + i;
                    st[r][c2] = fmaxf(U[(0 * 8 + r) * 256 + c2] + U[(1 * 8 + r) * 256 + c2] +
                                      U[(2 * 8 + r) * 256 + c2] + U[(3 * 8 + r) * 256 + c2] +
                                      b1_r, 0.f);
                }
            }
            __syncthreads();   // SYNC_G

            // ---------- FFN2 compute: wave wv = 16-wide c2-slice ----------
            {
                float acc[8];
                #pragma unroll
                for (int r = 0; r < 8; ++r) acc[r] = 0.f;
                #pragma unroll
                for (int i4 = 0; i4 < 4; ++i4) {
                    const int cc0 = wv * 16 + i4 * 4;
                    const float w0 = W2[(cc0 + 0) * D_ + lane];
                    const float w1 = W2[(cc0 + 1) * D_ + lane];
                    const float w2 = W2[(cc0 + 2) * D_ + lane];
                    const float w3 = W2[(cc0 + 3) * D_ + lane];
                    #pragma unroll
                    for (int r = 0; r < 8; ++r) {
                        const float4 s4 = *(const float4*)&st[r][cc0];
                        acc[r] = fmaf(s4.x, w0, fmaf(s4.y, w1, fmaf(s4.z, w2, fmaf(s4.w, w3, acc[r]))));
                    }
                }
                #pragma unroll
                for (int r = 0; r < 8; ++r) U[(wv * 8 + r) * 64 + lane] = acc[r];
            }
            __syncthreads();   // SYNC_H

            // ---------- FFN2 combine + k_i / y-update (tid<512) ----------
            if (tid < 512) {
                float f = b2_r;
                #pragma unroll
                for (int w = 0; w < 16; ++w) f += U[(w * 8 + r_own) * 64 + c_own];
                const float kv = so_reg + f;
                if (stage < 5) {
                    // static register select (no LDS, no scratch)
                    k1r = (stage == 0) ? kv : k1r;
                    k2r = (stage == 1) ? kv : k2r;
                    k3r = (stage == 2) ? kv : k3r;
                    k4r = (stage == 3) ? kv : k4r;
                    k5r = (stage == 4) ? kv : k5r;
                } else {
                    float yn = B_tab[0] * k1r;
                    yn = fmaf(B_tab[2], k3r, yn);
                    yn = fmaf(B_tab[3], k4r, yn);
                    yn = fmaf(B_tab[4], k5r, yn);
                    yn = fmaf(B_tab[5], kv, yn);
                    yn = fmaf(DTs, yn, ys_reg);
                    if (step < NSTEPS - 1) ys_reg = yn;
                    else out[(row0 + r_own) * D_ + c_own] = yn;
                }
            }
            // next stage's SYNC_A orders U reuse.
        }
    }
}

extern "C" void kernel_launch(void* const* d_in, const int* in_sizes, int n_in,
                              void* d_out, int out_size, void* d_ws, size_t ws_size,
                              hipStream_t stream) {
    const float* x  = (const float*)d_in[0];
    // d_in[1] = mask: broadcasts over the key axis -> softmax-invariant -> no-op.
    const float* Wq = (const float*)d_in[2];
    const float* bq = (const float*)d_in[3];
    const float* Wk = (const float*)d_in[4];
    const float* bk = (const float*)d_in[5];
    const float* Wv = (const float*)d_in[6];
    const float* bv = (const float*)d_in[7];
    const float* Wo = (const float*)d_in[8];
    const float* bo = (const float*)d_in[9];
    const float* W1 = (const float*)d_in[10];
    const float* b1 = (const float*)d_in[11];
    const float* W2 = (const float*)d_in[12];
    const float* b2 = (const float*)d_in[13];
    float* out  = (float*)d_out;

    float* base = (float*)d_ws;
    float* g_k  = base;                    // 2*N_*D_
    float* g_v  = g_k + 2 * N_ * D_;       // 2*N_*D_

    void* args[] = {
        (void*)&x,
        (void*)&Wq, (void*)&bq, (void*)&Wk, (void*)&bk,
        (void*)&Wv, (void*)&bv, (void*)&Wo, (void*)&bo,
        (void*)&W1, (void*)&b1, (void*)&W2, (void*)&b2,
        (void*)&out,
        (void*)&g_k, (void*)&g_v,
    };
    hipLaunchCooperativeKernel((void*)ode_enc_kernel, dim3(GWG), dim3(TPB),
                               args, 0, stream);
}

// Round 8
// 1313.941 us; speedup vs baseline: 1.3236x; 1.3236x over previous
//
#include <hip/hip_runtime.h>
#include <hip/hip_cooperative_groups.h>

namespace cg = cooperative_groups;

#define B_    4
#define S_    512
#define D_    64
#define DFF_  256
#define N_    2048          // B_*S_
#define GWG   256           // 1 block per CU (cooperative-safe)
#define TPB   1024          // 16 waves/block = 4 waves/SIMD
#define RPW   8             // rows per workgroup
#define NSTEPS 4
#define DTs   0.25f

__constant__ float A_tab[6][5] = {
    {0.f, 0.f, 0.f, 0.f, 0.f},
    {0.25f, 0.f, 0.f, 0.f, 0.f},
    {3.0f/32.0f, 9.0f/32.0f, 0.f, 0.f, 0.f},
    {1932.0f/2197.0f, -7200.0f/2197.0f, 7296.0f/2197.0f, 0.f, 0.f},
    {439.0f/216.0f, -8.0f, 3680.0f/513.0f, -845.0f/4104.0f, 0.f},
    {-8.0f/27.0f, 2.0f, -3544.0f/2565.0f, 1859.0f/4104.0f, -11.0f/40.0f}};
__constant__ float B_tab[6] = {16.0f/135.0f, 0.0f, 6656.0f/12825.0f,
                               28561.0f/56430.0f, -9.0f/50.0f, 2.0f/55.0f};

__global__ __launch_bounds__(TPB) void ode_enc_kernel(
    const float* __restrict__ x,
    const float* __restrict__ Wq, const float* __restrict__ bq,
    const float* __restrict__ Wk, const float* __restrict__ bk,
    const float* __restrict__ Wv, const float* __restrict__ bv,
    const float* __restrict__ Wo, const float* __restrict__ bo,
    const float* __restrict__ W1, const float* __restrict__ b1,
    const float* __restrict__ W2, const float* __restrict__ b2,
    float* __restrict__ out,
    float* __restrict__ g_k,    // [2][N_*D_] ping-pong K
    float* __restrict__ g_v)    // [2][N_*D_] ping-pong V
{
    cg::grid_group grid = cg::this_grid();
    const int wg   = blockIdx.x;
    const int tid  = threadIdx.x;
    const int lane = tid & 63;
    const int wv   = tid >> 6;            // wave id 0..15
    // XCD-aware swizzle: each XCD's 32 blocks serve one contiguous sid chunk
    const int sid  = (wg & 7) * 32 + (wg >> 3);
    const int row0  = sid * RPW;
    const int krow0 = (sid >> 6) * S_;    // batch base (64 sids per batch)

    const int r_own = wv & 7;             // for tid<512: owned (row, col)
    const int c_own = lane;

    __shared__ float sy[RPW][D_];         // stage input
    __shared__ float sqs[RPW][D_];        // Q projection (pre-scaled)
    __shared__ float satt[RPW][D_];       // attention output
    __shared__ float sh[RPW][D_];         // FFN input
    __shared__ float st[RPW][DFF_];       // relu(h@W1+b1)
    __shared__ float ysl[RPW][D_];        // persistent y  (same-thread access)
    __shared__ float kst[5][RPW][D_];     // RK slopes     (same-thread access)
    __shared__ float U[10240];            // partials union (40 KB)

    if (tid < 512) ysl[r_own][c_own] = x[(row0 + r_own) * D_ + c_own];
    const float bq_r = bq[c_own], bk_r = bk[c_own], bv_r = bv[c_own];
    const float bo_r = bo[c_own], b2_r = b2[c_own];
    const float b1_r = b1[tid & 255];
    const float SC = 0.51006702f;         // log2(e)/sqrt(8)

    for (int step = 0; step < NSTEPS; ++step) {
        for (int stage = 0; stage < 6; ++stage) {
            const int buf = (step * 6 + stage) & 1;

            // ---------- P1: RK stage input (branchless tableau) ----------
            float stin = 0.f;
            if (tid < 512) {
                stin = ysl[r_own][c_own];
                stin = fmaf(DTs * A_tab[stage][0], kst[0][r_own][c_own], stin);
                stin = fmaf(DTs * A_tab[stage][1], kst[1][r_own][c_own], stin);
                stin = fmaf(DTs * A_tab[stage][2], kst[2][r_own][c_own], stin);
                stin = fmaf(DTs * A_tab[stage][3], kst[3][r_own][c_own], stin);
                stin = fmaf(DTs * A_tab[stage][4], kst[4][r_own][c_own], stin);
                sy[r_own][c_own] = stin;
            }
            __syncthreads();   // SYNC_A (also orders U reuse)

            // ---------- QKV compute: waves 0..11 = (mat, d-quarter) ----------
            if (wv < 12) {
                const int mat = wv >> 2, p = wv & 3;
                const float* Wm = (mat == 0) ? Wq : (mat == 1) ? Wk : Wv;
                float acc[8];
                #pragma unroll
                for (int r = 0; r < 8; ++r) acc[r] = 0.f;
                #pragma unroll
                for (int i4 = 0; i4 < 4; ++i4) {
                    const int dd0 = p * 16 + i4 * 4;
                    const float w0 = Wm[(dd0 + 0) * D_ + lane];
                    const float w1 = Wm[(dd0 + 1) * D_ + lane];
                    const float w2 = Wm[(dd0 + 2) * D_ + lane];
                    const float w3 = Wm[(dd0 + 3) * D_ + lane];
                    #pragma unroll
                    for (int r = 0; r < 8; ++r) {
                        const float4 s4 = *(const float4*)&sy[r][dd0];
                        acc[r] = fmaf(s4.x, w0, fmaf(s4.y, w1, fmaf(s4.z, w2, fmaf(s4.w, w3, acc[r]))));
                    }
                }
                #pragma unroll
                for (int r = 0; r < 8; ++r) U[(wv * 8 + r) * 64 + lane] = acc[r];
            }
            __syncthreads();   // SYNC_B

            // ---------- QKV combine (tid<512) ----------
            if (tid < 512) {
                float qa = bq_r, ka = bk_r, va = bv_r;
                #pragma unroll
                for (int p = 0; p < 4; ++p) {
                    qa += U[((0 + p) * 8 + r_own) * 64 + c_own];
                    ka += U[((4 + p) * 8 + r_own) * 64 + c_own];
                    va += U[((8 + p) * 8 + r_own) * 64 + c_own];
                }
                sqs[r_own][c_own] = qa * SC;   // pre-scaled Q
                const size_t kidx = ((size_t)buf * N_ + row0 + r_own) * D_ + c_own;
                g_k[kidx] = ka;
                g_v[kidx] = va;
            }
            grid.sync();       // K/V of the whole batch visible

            // ---------- attention: wave = 32-key slice, lane = (head, row) ----------
            // 8 lanes sharing a head read identical addresses (broadcast);
            // K+V read exactly once per block per stage. 2-deep batching
            // (32 live K/V floats) to stay well under the 128-VGPR cap.
            {
                const int h = lane & 7;        // head
                const int r = lane >> 3;       // q-row
                float qv[8];
                {
                    const float4 qa = *(const float4*)&sqs[r][h * 8];
                    const float4 qb = *(const float4*)&sqs[r][h * 8 + 4];
                    qv[0] = qa.x; qv[1] = qa.y; qv[2] = qa.z; qv[3] = qa.w;
                    qv[4] = qb.x; qv[5] = qb.y; qv[6] = qb.z; qv[7] = qb.w;
                }
                const float* kb = g_k + ((size_t)buf * N_ + krow0 + wv * 32) * D_ + h * 8;
                const float* vb = g_v + ((size_t)buf * N_ + krow0 + wv * 32) * D_ + h * 8;

                float m = -1e30f, l = 0.f;
                float acc8[8];
                #pragma unroll
                for (int d = 0; d < 8; ++d) acc8[d] = 0.f;

                for (int j0 = 0; j0 < 32; j0 += 2) {
                    float4 kA[2], kB[2], vA[2], vB[2];
                    #pragma unroll
                    for (int u = 0; u < 2; ++u) {
                        const float* kr = kb + (size_t)(j0 + u) * D_;
                        kA[u] = *(const float4*)kr;
                        kB[u] = *(const float4*)(kr + 4);
                    }
                    #pragma unroll
                    for (int u = 0; u < 2; ++u) {
                        const float* vr = vb + (size_t)(j0 + u) * D_;
                        vA[u] = *(const float4*)vr;
                        vB[u] = *(const float4*)(vr + 4);
                    }
                    float s0, s1;
                    s0 = fmaf(qv[0],kA[0].x,fmaf(qv[1],kA[0].y,fmaf(qv[2],kA[0].z,fmaf(qv[3],kA[0].w,
                         fmaf(qv[4],kB[0].x,fmaf(qv[5],kB[0].y,fmaf(qv[6],kB[0].z,qv[7]*kB[0].w)))))));
                    s1 = fmaf(qv[0],kA[1].x,fmaf(qv[1],kA[1].y,fmaf(qv[2],kA[1].z,fmaf(qv[3],kA[1].w,
                         fmaf(qv[4],kB[1].x,fmaf(qv[5],kB[1].y,fmaf(qv[6],kB[1].z,qv[7]*kB[1].w)))))));

                    const float bm = fmaxf(s0, s1);
                    if (bm > m + 8.f) {        // deferred-rescale (T13)
                        const float al = exp2f(m - bm);
                        m = bm; l *= al;
                        #pragma unroll
                        for (int d = 0; d < 8; ++d) acc8[d] *= al;
                    }
                    const float p0 = exp2f(s0 - m);
                    const float p1 = exp2f(s1 - m);
                    l += p0 + p1;
                    acc8[0] = fmaf(p0,vA[0].x,fmaf(p1,vA[1].x,acc8[0]));
                    acc8[1] = fmaf(p0,vA[0].y,fmaf(p1,vA[1].y,acc8[1]));
                    acc8[2] = fmaf(p0,vA[0].z,fmaf(p1,vA[1].z,acc8[2]));
                    acc8[3] = fmaf(p0,vA[0].w,fmaf(p1,vA[1].w,acc8[3]));
                    acc8[4] = fmaf(p0,vB[0].x,fmaf(p1,vB[1].x,acc8[4]));
                    acc8[5] = fmaf(p0,vB[0].y,fmaf(p1,vB[1].y,acc8[5]));
                    acc8[6] = fmaf(p0,vB[0].z,fmaf(p1,vB[1].z,acc8[6]));
                    acc8[7] = fmaf(p0,vB[0].w,fmaf(p1,vB[1].w,acc8[7]));
                }
                // write partial (acc8, m, l) for (key-slice wv, row r, head h)
                const int pb = ((wv * 8 + r) * 8 + h) * 10;
                #pragma unroll
                for (int d = 0; d < 8; ++d) U[pb + d] = acc8[d];
                U[pb + 8] = m;
                U[pb + 9] = l;
            }
            __syncthreads();   // SYNC_C1

            // ---------- online merge of 16 key-slice partials (tid<512) ----------
            if (tid < 512) {
                const int h = c_own >> 3, d = c_own & 7;
                float M = -1e30f, L = 0.f, A = 0.f;
                #pragma unroll
                for (int w = 0; w < 16; ++w) {
                    const int pb = ((w * 8 + r_own) * 8 + h) * 10;
                    const float mm = U[pb + 8];
                    const float ll = U[pb + 9];
                    const float aa = U[pb + d];
                    const float Mn = fmaxf(M, mm);
                    const float f  = exp2f(M - Mn);
                    const float g  = exp2f(mm - Mn);
                    L = L * f + ll * g;
                    A = A * f + aa * g;
                    M = Mn;
                }
                satt[r_own][c_own] = A * __builtin_amdgcn_rcpf(L);
            }
            __syncthreads();   // SYNC_C2

            // ---------- Wo compute: wave wv = 4-row d-slice ----------
            {
                const int dd0 = wv * 4;
                const float w0 = Wo[(dd0 + 0) * D_ + lane];
                const float w1 = Wo[(dd0 + 1) * D_ + lane];
                const float w2 = Wo[(dd0 + 2) * D_ + lane];
                const float w3 = Wo[(dd0 + 3) * D_ + lane];
                float acc[8];
                #pragma unroll
                for (int r = 0; r < 8; ++r) {
                    const float4 s4 = *(const float4*)&satt[r][dd0];
                    acc[r] = fmaf(s4.x, w0, fmaf(s4.y, w1, fmaf(s4.z, w2, s4.w * w3)));
                }
                #pragma unroll
                for (int r = 0; r < 8; ++r) U[(wv * 8 + r) * 64 + lane] = acc[r];
            }
            __syncthreads();   // SYNC_D

            // ---------- Wo combine (tid<512) ----------
            float so_reg = 0.f;
            if (tid < 512) {
                float a = bo_r;
                #pragma unroll
                for (int w = 0; w < 16; ++w) a += U[(w * 8 + r_own) * 64 + c_own];
                so_reg = a;
                sh[r_own][c_own] = stin + a;
            }
            __syncthreads();   // SYNC_E

            // ---------- FFN1 compute: thread = (c2, d-quarter) ----------
            {
                const int c2 = tid & 255, p = tid >> 8;
                float acc[8];
                #pragma unroll
                for (int r = 0; r < 8; ++r) acc[r] = 0.f;
                #pragma unroll
                for (int i4 = 0; i4 < 4; ++i4) {
                    const int dd0 = p * 16 + i4 * 4;
                    const float w0 = W1[(dd0 + 0) * DFF_ + c2];
                    const float w1 = W1[(dd0 + 1) * DFF_ + c2];
                    const float w2 = W1[(dd0 + 2) * DFF_ + c2];
                    const float w3 = W1[(dd0 + 3) * DFF_ + c2];
                    #pragma unroll
                    for (int r = 0; r < 8; ++r) {
                        const float4 s4 = *(const float4*)&sh[r][dd0];
                        acc[r] = fmaf(s4.x, w0, fmaf(s4.y, w1, fmaf(s4.z, w2, fmaf(s4.w, w3, acc[r]))));
                    }
                }
                #pragma unroll
                for (int r = 0; r < 8; ++r) U[(p * 8 + r) * 256 + c2] = acc[r];
            }
            __syncthreads();   // SYNC_F

            // ---------- FFN1 combine: thread = (c2, row-pair) ----------
            {
                const int c2 = tid & 255, rb = (tid >> 8) * 2;
                #pragma unroll
                for (int i = 0; i < 2; ++i) {
                    const int r = rb + i;
                    st[r][c2] = fmaxf(U[(0 * 8 + r) * 256 + c2] + U[(1 * 8 + r) * 256 + c2] +
                                      U[(2 * 8 + r) * 256 + c2] + U[(3 * 8 + r) * 256 + c2] +
                                      b1_r, 0.f);
                }
            }
            __syncthreads();   // SYNC_G

            // ---------- FFN2 compute: wave wv = 16-wide c2-slice ----------
            {
                float acc[8];
                #pragma unroll
                for (int r = 0; r < 8; ++r) acc[r] = 0.f;
                #pragma unroll
                for (int i4 = 0; i4 < 4; ++i4) {
                    const int cc0 = wv * 16 + i4 * 4;
                    const float w0 = W2[(cc0 + 0) * D_ + lane];
                    const float w1 = W2[(cc0 + 1) * D_ + lane];
                    const float w2 = W2[(cc0 + 2) * D_ + lane];
                    const float w3 = W2[(cc0 + 3) * D_ + lane];
                    #pragma unroll
                    for (int r = 0; r < 8; ++r) {
                        const float4 s4 = *(const float4*)&st[r][cc0];
                        acc[r] = fmaf(s4.x, w0, fmaf(s4.y, w1, fmaf(s4.z, w2, fmaf(s4.w, w3, acc[r]))));
                    }
                }
                #pragma unroll
                for (int r = 0; r < 8; ++r) U[(wv * 8 + r) * 64 + lane] = acc[r];
            }
            __syncthreads();   // SYNC_H

            // ---------- FFN2 combine + k_i / y-update (tid<512) ----------
            if (tid < 512) {
                float f = b2_r;
                #pragma unroll
                for (int w = 0; w < 16; ++w) f += U[(w * 8 + r_own) * 64 + c_own];
                const float kv = so_reg + f;
                if (stage < 5) {
                    kst[stage][r_own][c_own] = kv;
                } else {
                    float yn = B_tab[0] * kst[0][r_own][c_own];
                    yn = fmaf(B_tab[2], kst[2][r_own][c_own], yn);
                    yn = fmaf(B_tab[3], kst[3][r_own][c_own], yn);
                    yn = fmaf(B_tab[4], kst[4][r_own][c_own], yn);
                    yn = fmaf(B_tab[5], kv, yn);
                    yn = fmaf(DTs, yn, ysl[r_own][c_own]);
                    if (step < NSTEPS - 1) ysl[r_own][c_own] = yn;
                    else out[(row0 + r_own) * D_ + c_own] = yn;
                }
            }
            // next stage's SYNC_A orders U reuse; ysl/kst are same-thread.
        }
    }
}

extern "C" void kernel_launch(void* const* d_in, const int* in_sizes, int n_in,
                              void* d_out, int out_size, void* d_ws, size_t ws_size,
                              hipStream_t stream) {
    const float* x  = (const float*)d_in[0];
    // d_in[1] = mask: broadcasts over the key axis -> softmax-invariant -> no-op.
    const float* Wq = (const float*)d_in[2];
    const float* bq = (const float*)d_in[3];
    const float* Wk = (const float*)d_in[4];
    const float* bk = (const float*)d_in[5];
    const float* Wv = (const float*)d_in[6];
    const float* bv = (const float*)d_in[7];
    const float* Wo = (const float*)d_in[8];
    const float* bo = (const float*)d_in[9];
    const float* W1 = (const float*)d_in[10];
    const float* b1 = (const float*)d_in[11];
    const float* W2 = (const float*)d_in[12];
    const float* b2 = (const float*)d_in[13];
    float* out  = (float*)d_out;

    float* base = (float*)d_ws;
    float* g_k  = base;                    // 2*N_*D_
    float* g_v  = g_k + 2 * N_ * D_;       // 2*N_*D_

    void* args[] = {
        (void*)&x,
        (void*)&Wq, (void*)&bq, (void*)&Wk, (void*)&bk,
        (void*)&Wv, (void*)&bv, (void*)&Wo, (void*)&bo,
        (void*)&W1, (void*)&b1, (void*)&W2, (void*)&b2,
        (void*)&out,
        (void*)&g_k, (void*)&g_v,
    };
    hipLaunchCooperativeKernel((void*)ode_enc_kernel, dim3(GWG), dim3(TPB),
                               args, 0, stream);
}